// Round 6
// baseline (85.878 us; speedup 1.0000x reference)
//
#include <hip/hip_runtime.h>
#include <hip/hip_bf16.h>

// Problem constants (fixed by reference)
#define NB    2
#define HW    25600      // 160*160
#define WDIM  160
#define NSTG  9

// ---- DPP add (full-rate VALU, no LDS pipe) ----
template <int CTRL>
__device__ __forceinline__ float dpp_add(float v) {
    int moved = __builtin_amdgcn_update_dpp(0, __float_as_int(v), CTRL, 0xf, 0xf, true);
    return v + __int_as_float(moved);
}

// sum over each 16-lane row, broadcast to all 16 lanes — 4 pure-DPP adds.
__device__ __forceinline__ float reduce16(float v) {
    v = dpp_add<0xB1>(v);    // quad_perm [1,0,3,2] : xor 1
    v = dpp_add<0x4E>(v);    // quad_perm [2,3,0,1] : xor 2
    v = dpp_add<0x141>(v);   // row_half_mirror     : completes each 8-group
    v = dpp_add<0x140>(v);   // row_mirror          : cross 8-group within 16
    return v;
}

// One fused kernel: head 1x1 conv (recomputed per gather position),
// rank-collapsed 9-stage iteration, tail 1x1 conv.
// Layout: 16 lanes per pixel, 2 channels per lane -> 4 px/wave, 16 px/block.
// VGPR footprint kept <= 64 so launch_bounds(256,8) gives 8 waves/SIMD.
__global__ __launch_bounds__(256, 8) void fused_kernel(const float* __restrict__ x,
                                                       const float* __restrict__ head_w,
                                                       const float* __restrict__ tail_w,
                                                       const float* __restrict__ alphas,
                                                       const float* __restrict__ betas,
                                                       float* __restrict__ out) {
    int sub = threadIdx.x & 15;              // channel pair: channels 2*sub, 2*sub+1
    int pid = blockIdx.x * 16 + (threadIdx.x >> 4);
    int b   = blockIdx.x / 1600;             // 16 px/block -> 1600 blocks per image
    int s2  = pid - b * HW;

    // head weights for my 2 channels: head_w is [32][3]
    int c0 = sub * 2;
    const float* hwp = head_w + c0 * 3;
    float hw00 = hwp[0], hw01 = hwp[1], hw02 = hwp[2];
    float hw10 = hwp[3], hw11 = hwp[4], hw12 = hwp[5];

    const float* xb0 = x + b * 3 * HW;
    const float* xb1 = xb0 + HW;
    const float* xb2 = xb1 + HW;

    // Unfold+reshape scramble (channel-preserving): g = s2*9+k2, kk = g/HW
    // (constant per pixel except at most one wrap), l = g%HW.
    int g9  = s2 * 9;
    int kk0 = g9 / HW;
    int r0  = g9 - kk0 * HW;
    int h0  = r0 / WDIM;
    int w0  = r0 - h0 * WDIM;
    int ki0 = kk0 / 3;
    int dh0 = ki0 - 1, dw0 = kk0 - ki0 * 3 - 1;
    int kk1 = kk0 + 1;
    int ki1 = kk1 / 3;
    int dh1 = ki1 - 1, dw1 = kk1 - ki1 * 3 - 1;

    float X[9][2];
#pragma unroll
    for (int k2 = 0; k2 < 9; ++k2) {
        int r  = r0 + k2;
        int wn = w0 + k2;
        int cw = (wn >= WDIM);
        int w1 = cw ? wn - WDIM : wn;
        int h1 = h0 + cw;
        bool wr = (r >= HW);
        int h  = wr ? 0 : h1;
        int w  = wr ? r - HW : w1;
        int dh = wr ? dh1 : dh0;
        int dw = wr ? dw1 : dw0;
        int hh = min(max(h + dh, 0), 159);
        int ww = min(max(w + dw, 0), 159);
        int p  = hh * WDIM + ww;
        float x0 = xb0[p], x1 = xb1[p], x2 = xb2[p];
        X[k2][0] = fmaxf(hw00 * x0 + hw01 * x1 + hw02 * x2, 0.f);
        X[k2][1] = fmaxf(hw10 * x0 + hw11 * x1 + hw12 * x2, 0.f);
    }

    // init: u[c] = mean_k X ; v[k] = mean_c X
    float u[2];
#pragma unroll
    for (int j = 0; j < 2; ++j) {
        float a = (((X[0][j] + X[1][j]) + (X[2][j] + X[3][j]))
                +  ((X[4][j] + X[5][j]) + (X[6][j] + X[7][j]))) + X[8][j];
        u[j] = a * (1.f / 9.f);
    }
    float v[9];
#pragma unroll
    for (int k = 0; k < 9; ++k)
        v[k] = reduce16(X[k][0] + X[k][1]) * (1.f / 32.f);

    // 9 stages (rank-collapsed: all 3 ranks provably identical)
#pragma unroll
    for (int i = 0; i < NSTG; ++i) {
        float beta  = betas[i];
        float alpha = alphas[i];
        float s  = reduce16(u[0] * u[0] + u[1] * u[1]);
        float vs = 1.f - 3.f * beta * s;
#pragma unroll
        for (int k = 0; k < 9; ++k) {
            float q = reduce16(u[0] * X[k][0] + u[1] * X[k][1]);
            v[k] = v[k] * vs + beta * q;
        }
        float t = (((v[0] * v[0] + v[1] * v[1]) + (v[2] * v[2] + v[3] * v[3]))
                +  ((v[4] * v[4] + v[5] * v[5]) + (v[6] * v[6] + v[7] * v[7])))
                +   v[8] * v[8];
        float us = 1.f - 3.f * alpha * t;
#pragma unroll
        for (int j = 0; j < 2; ++j) {
            float m = ((X[0][j] * v[0] + X[1][j] * v[1]) + (X[2][j] * v[2] + X[3][j] * v[3]))
                    + ((X[4][j] * v[4] + X[5][j] * v[5]) + (X[6][j] * v[6] + X[7][j] * v[7]))
                    +   X[8][j] * v[8];
            u[j] = u[j] * us + alpha * m;
        }
    }

    // epilogue: UVc[c] = 3*u[c]*v[center=4]; out[o] = relu(sum_c UVc * tail_w[o*32+c])
    float v4 = v[4];
    float uvc0 = 3.f * u[0] * v4;
    float uvc1 = 3.f * u[1] * v4;
    float o[3];
#pragma unroll
    for (int oo = 0; oo < 3; ++oo) {
        const float* tw = tail_w + oo * 32 + c0;
        o[oo] = fmaxf(reduce16(uvc0 * tw[0] + uvc1 * tw[1]), 0.f);
    }
    if (sub == 0) {
        float* op = out + b * 3 * HW + s2;
        op[0]      = o[0];
        op[HW]     = o[1];
        op[2 * HW] = o[2];
    }
}

extern "C" void kernel_launch(void* const* d_in, const int* in_sizes, int n_in,
                              void* d_out, int out_size, void* d_ws, size_t ws_size,
                              hipStream_t stream) {
    const float* x      = (const float*)d_in[0];
    const float* head_w = (const float*)d_in[1];
    const float* tail_w = (const float*)d_in[2];
    const float* alphas = (const float*)d_in[3];
    const float* betas  = (const float*)d_in[4];
    float*       out    = (float*)d_out;

    // NB*HW pixels, 4 px/wave, 16 px/block -> 3200 blocks of 256
    fused_kernel<<<dim3(NB * HW / 16), dim3(256), 0, stream>>>(
        x, head_w, tail_w, alphas, betas, out);
}

// Round 7
// 76.108 us; speedup vs baseline: 1.1284x; 1.1284x over previous
//
#include <hip/hip_runtime.h>
#include <hip/hip_bf16.h>

// Problem constants (fixed by reference)
#define NB    2
#define HW    25600      // 160*160
#define WDIM  160
#define NSTG  9

typedef float f2 __attribute__((ext_vector_type(2)));   // -> v_pk_*_f32

// ---- DPP add (full-rate VALU, no LDS pipe) ----
template <int CTRL>
__device__ __forceinline__ float dpp_add(float v) {
    int moved = __builtin_amdgcn_update_dpp(0, __float_as_int(v), CTRL, 0xf, 0xf, true);
    return v + __int_as_float(moved);
}

// sum over each 4-lane quad, broadcast to all 4 lanes — 2 quad_perm DPP adds.
__device__ __forceinline__ float reduce4(float v) {
    v = dpp_add<0xB1>(v);    // quad_perm [1,0,3,2] : xor 1
    v = dpp_add<0x4E>(v);    // quad_perm [2,3,0,1] : xor 2
    return v;
}

// One fused kernel: head 1x1 conv (recomputed per gather position),
// rank-collapsed 9-stage iteration, tail 1x1 conv.
// Layout: 4 lanes/pixel, 8 channels/lane as 4 float2 (v_pk_fma_f32),
// 16 pixels/wave, 800 blocks. Same shape as R4; ~35% fewer VALU instrs.
__global__ __launch_bounds__(256, 3) void fused_kernel(const float* __restrict__ x,
                                                       const float* __restrict__ head_w,
                                                       const float* __restrict__ tail_w,
                                                       const float* __restrict__ alphas,
                                                       const float* __restrict__ betas,
                                                       float* __restrict__ out) {
    int sub = threadIdx.x & 3;               // channel octet: channels 8*sub .. 8*sub+7
    int pid = blockIdx.x * 64 + (threadIdx.x >> 2);   // 64 pixels/block
    int b   = blockIdx.x / 400;              // 400 blocks per batch image
    int s2  = pid - b * HW;

    // head weights for my 8 channels (4 pairs): hwc[ci][jj] = {w[c,ci], w[c+1,ci]}
    int c0 = sub * 8;
    f2 hwc[3][4];
#pragma unroll
    for (int jj = 0; jj < 4; ++jj) {
        const float* p0 = head_w + (c0 + 2 * jj) * 3;
#pragma unroll
        for (int ci = 0; ci < 3; ++ci)
            hwc[ci][jj] = (f2){p0[ci], p0[3 + ci]};
    }

    const float* xb0 = x + b * 3 * HW;
    const float* xb1 = xb0 + HW;
    const float* xb2 = xb1 + HW;

    // Unfold+reshape scramble (channel-preserving): g = s2*9+k2, kk = g/HW
    // (constant per pixel except at most one wrap), l = g%HW.
    int g9  = s2 * 9;
    int kk0 = g9 / HW;
    int r0  = g9 - kk0 * HW;
    int h0  = r0 / WDIM;
    int w0  = r0 - h0 * WDIM;
    int ki0 = kk0 / 3;
    int dh0 = ki0 - 1, dw0 = kk0 - ki0 * 3 - 1;
    int kk1 = kk0 + 1;
    int ki1 = kk1 / 3;
    int dh1 = ki1 - 1, dw1 = kk1 - ki1 * 3 - 1;

    f2 X[9][4];
#pragma unroll
    for (int k2 = 0; k2 < 9; ++k2) {
        int r  = r0 + k2;
        int wn = w0 + k2;
        int cw = (wn >= WDIM);
        int w1 = cw ? wn - WDIM : wn;
        int h1 = h0 + cw;
        bool wr = (r >= HW);
        int h  = wr ? 0 : h1;
        int w  = wr ? r - HW : w1;
        int dh = wr ? dh1 : dh0;
        int dw = wr ? dw1 : dw0;
        int hh = min(max(h + dh, 0), 159);
        int ww = min(max(w + dw, 0), 159);
        int p  = hh * WDIM + ww;
        f2 xx0 = (f2)(xb0[p]);     // broadcast
        f2 xx1 = (f2)(xb1[p]);
        f2 xx2 = (f2)(xb2[p]);
#pragma unroll
        for (int jj = 0; jj < 4; ++jj) {
            f2 r2 = hwc[0][jj] * xx0 + hwc[1][jj] * xx1 + hwc[2][jj] * xx2;
            X[k2][jj] = __builtin_elementwise_max(r2, (f2)(0.f));
        }
    }

    // init: u[c] = mean_k X ; v[k] = mean_c X
    f2 u[4];
#pragma unroll
    for (int jj = 0; jj < 4; ++jj) {
        f2 a = (((X[0][jj] + X[1][jj]) + (X[2][jj] + X[3][jj]))
             +  ((X[4][jj] + X[5][jj]) + (X[6][jj] + X[7][jj]))) + X[8][jj];
        u[jj] = a * (1.f / 9.f);
    }
    float v[9];
#pragma unroll
    for (int k = 0; k < 9; ++k) {
        f2 pr = (X[k][0] + X[k][1]) + (X[k][2] + X[k][3]);
        v[k] = reduce4(pr.x + pr.y) * (1.f / 32.f);
    }

    // 9 stages (rank-collapsed: all 3 ranks provably identical)
#pragma unroll
    for (int i = 0; i < NSTG; ++i) {
        float beta  = betas[i];
        float alpha = alphas[i];
        f2 sp = (u[0] * u[0] + u[1] * u[1]) + (u[2] * u[2] + u[3] * u[3]);
        float s  = reduce4(sp.x + sp.y);
        float vs = 1.f - 3.f * beta * s;
#pragma unroll
        for (int k = 0; k < 9; ++k) {
            f2 qp = (u[0] * X[k][0] + u[1] * X[k][1]) + (u[2] * X[k][2] + u[3] * X[k][3]);
            float q = reduce4(qp.x + qp.y);
            v[k] = v[k] * vs + beta * q;
        }
        float t = (((v[0] * v[0] + v[1] * v[1]) + (v[2] * v[2] + v[3] * v[3]))
                +  ((v[4] * v[4] + v[5] * v[5]) + (v[6] * v[6] + v[7] * v[7])))
                +   v[8] * v[8];
        float us = 1.f - 3.f * alpha * t;
#pragma unroll
        for (int jj = 0; jj < 4; ++jj) {
            f2 m = ((X[0][jj] * v[0] + X[1][jj] * v[1]) + (X[2][jj] * v[2] + X[3][jj] * v[3]))
                 + ((X[4][jj] * v[4] + X[5][jj] * v[5]) + (X[6][jj] * v[6] + X[7][jj] * v[7]))
                 +   X[8][jj] * v[8];
            u[jj] = u[jj] * us + alpha * m;
        }
    }

    // epilogue: UVc[c] = 3*u[c]*v[center=4]; out[o] = relu(sum_c UVc * tail_w[o*32+c])
    float v4 = v[4];
    f2 uvc[4];
#pragma unroll
    for (int jj = 0; jj < 4; ++jj) uvc[jj] = u[jj] * (3.f * v4);
    float o[3];
#pragma unroll
    for (int oo = 0; oo < 3; ++oo) {
        const float* tw = tail_w + oo * 32 + c0;
        f2 t0 = {tw[0], tw[1]}, t1 = {tw[2], tw[3]}, t2 = {tw[4], tw[5]}, t3 = {tw[6], tw[7]};
        f2 pr = (uvc[0] * t0 + uvc[1] * t1) + (uvc[2] * t2 + uvc[3] * t3);
        o[oo] = fmaxf(reduce4(pr.x + pr.y), 0.f);
    }
    if (sub == 0) {
        float* op = out + b * 3 * HW + s2;
        op[0]      = o[0];
        op[HW]     = o[1];
        op[2 * HW] = o[2];
    }
}

extern "C" void kernel_launch(void* const* d_in, const int* in_sizes, int n_in,
                              void* d_out, int out_size, void* d_ws, size_t ws_size,
                              hipStream_t stream) {
    const float* x      = (const float*)d_in[0];
    const float* head_w = (const float*)d_in[1];
    const float* tail_w = (const float*)d_in[2];
    const float* alphas = (const float*)d_in[3];
    const float* betas  = (const float*)d_in[4];
    float*       out    = (float*)d_out;

    // NB*HW pixels * 4 lanes/pixel = 204800 threads -> 800 blocks of 256
    fused_kernel<<<dim3(NB * HW * 4 / 256), dim3(256), 0, stream>>>(
        x, head_w, tail_w, alphas, betas, out);
}